// Round 1
// baseline (645.700 us; speedup 1.0000x reference)
//
#include <hip/hip_runtime.h>
#include <math.h>

// ---------------------------------------------------------------------------
// Problem constants: L=512, C=16, B=8, D=512, TOP_K=5, E=43 experts
// out0: emb_all [8, 16, 1657, 512] f32 ; out1: gates [8, 43] f32
// ---------------------------------------------------------------------------

typedef float v2f __attribute__((ext_vector_type(2)));

constexpr int NEXP = 43;
constexpr int NTOT = 1657;                       // total patches
constexpr long long GATES_OFF = 108593152LL;     // 8*16*1657*512

// workspace layout (float offsets)
constexpr int WS_XR  = 0;       // [8,256]
constexpr int WS_XI  = 2048;    // [8,256]
constexpr int WS_O1R = 4096;    // [8,1024]
constexpr int WS_O1I = 12288;   // [8,1024]
constexpr int WS_LG  = 20480;   // [8,43]
constexpr int WS_PEF = 24576;   // pe_feat [16,256]
constexpr int WS_PEP = 28672;   // pe_pos  [256,256]

struct Tables {
  int P[NEXP];    // patch size
  int N[NEXP];    // ceil(512/p)
  int SL[NEXP];   // log2(split)
  int G0[NEXP];   // patch prefix
  int T0[NEXP+1]; // tile prefix
  int ne;
};

constexpr Tables make_tables() {
  Tables t{};
  int ne = 0;
  for (int p = 2; p <= 512; ++p) {
    int k = 512 / p;                 // k in [1,256]
    if (k >= 1 && k <= 256 && 512 / k == p) { t.P[ne] = p; ++ne; }
  }
  t.ne = ne;
  int g = 0, tl = 0;
  for (int i = 0; i < ne; ++i) {
    int p = t.P[i];
    int n = (512 + p - 1) / p;
    t.N[i] = n;
    int s  = (p >= 512) ? 16 : (p >= 170) ? 8 : (p >= 102) ? 4 : (p >= 64) ? 2 : 1;
    int sl = (s == 16) ? 4 : (s == 8) ? 3 : (s == 4) ? 2 : (s == 2) ? 1 : 0;
    t.SL[i] = sl;
    t.G0[i] = g;  g  += n;
    t.T0[i] = tl; tl += n * s;
  }
  t.T0[ne] = tl;
  return t;
}

constexpr Tables HTBL = make_tables();
static_assert(HTBL.ne == 43, "expert count");
static_assert(HTBL.G0[42] + HTBL.N[42] == 1657, "total patches");
static_assert(HTBL.T0[43] == 1767, "total tiles");

__constant__ Tables TBL = make_tables();

// ---------------------------------------------------------------------------
// G1: xs = x @ w_start + b ; rFFT(512, ortho)[1:] -> xr, xi  [8,256]
// ---------------------------------------------------------------------------
__global__ void k_dft(const float* __restrict__ x, const float* __restrict__ w_start,
                      const float* __restrict__ b_start, float* __restrict__ ws) {
  __shared__ float xs[512];
  int b = blockIdx.x, t = threadIdx.x;
  float w[16];
#pragma unroll
  for (int c = 0; c < 16; ++c) w[c] = w_start[c];
  float bs = b_start[0];
  for (int l = t; l < 512; l += 256) {
    const float* xp = x + ((size_t)b * 512 + l) * 16;
    float s = bs;
#pragma unroll
    for (int c = 0; c < 16; ++c) s = fmaf(xp[c], w[c], s);
    xs[l] = s;
  }
  __syncthreads();
  int k = t + 1;                       // frequencies 1..256
  float ar = 0.f, ai = 0.f;
  int ph = 0;                          // integer phase (k*l mod 512), exact
  for (int l = 0; l < 512; ++l) {
    float a  = (float)ph * (1.0f / 256.0f);   // angle / pi
    float cv = cospif(a), sv = sinpif(a);
    float v  = xs[l];
    ar = fmaf(v,  cv, ar);
    ai = fmaf(-v, sv, ai);             // exp(-i*2*pi*k*l/512)
    ph = (ph + k) & 511;
  }
  const float sc = 0.044194173824159216f;     // 1/sqrt(512)
  ws[WS_XR + b * 256 + t] = ar * sc;
  ws[WS_XI + b * 256 + t] = ai * sc;
}

// ---------------------------------------------------------------------------
// G2: layer1 (complex 256 -> 1024) + relu
// ---------------------------------------------------------------------------
__global__ void k_fc1(const float* __restrict__ w1, const float* __restrict__ b1,
                      float* __restrict__ ws) {
  __shared__ float xr[256], xi[256];
  int b = blockIdx.x >> 2, jg = blockIdx.x & 3, t = threadIdx.x;
  xr[t] = ws[WS_XR + b * 256 + t];
  xi[t] = ws[WS_XI + b * 256 + t];
  __syncthreads();
  int j = jg * 256 + t;
  float s_ra = 0.f, s_rb = 0.f, s_ia = 0.f, s_ib = 0.f;
  for (int k = 0; k < 256; ++k) {
    float a  = w1[k * 1024 + j];            // w1[0][k][j]
    float bb = w1[262144 + k * 1024 + j];   // w1[1][k][j]
    float r = xr[k], im = xi[k];
    s_ra = fmaf(r, a, s_ra);  s_ib = fmaf(im, bb, s_ib);
    s_ia = fmaf(im, a, s_ia); s_rb = fmaf(r, bb, s_rb);
  }
  float o1r = s_ra - s_ib + b1[j];
  float o1i = s_ia + s_rb + b1[1024 + j];
  ws[WS_O1R + b * 1024 + j] = fmaxf(o1r, 0.f);
  ws[WS_O1I + b * 1024 + j] = fmaxf(o1i, 0.f);
}

// ---------------------------------------------------------------------------
// G3: layer2 (complex 1024 -> 256) + softshrink + amp + logits [8,43]
// ---------------------------------------------------------------------------
__device__ __forceinline__ float softshrink(float v) {
  const float l = 0.01f;
  return v > l ? v - l : (v < -l ? v + l : 0.f);
}

__global__ void k_fc2(const float* __restrict__ w2, const float* __restrict__ b2,
                      const float* __restrict__ w_gate, float* __restrict__ ws) {
  __shared__ float o1r[1024], o1i[1024], amp[256];
  int b = blockIdx.x, t = threadIdx.x;
  for (int k = t; k < 1024; k += 256) {
    o1r[k] = ws[WS_O1R + b * 1024 + k];
    o1i[k] = ws[WS_O1I + b * 1024 + k];
  }
  __syncthreads();
  float s_rr = 0.f, s_ri = 0.f, s_ir = 0.f, s_ii = 0.f;
  for (int k = 0; k < 1024; ++k) {
    float a  = w2[k * 256 + t];             // w2[0][k][t]
    float bb = w2[262144 + k * 256 + t];    // w2[1][k][t]
    float r = o1r[k], im = o1i[k];
    s_rr = fmaf(r, a, s_rr);  s_ii = fmaf(im, bb, s_ii);
    s_ir = fmaf(im, a, s_ir); s_ri = fmaf(r, bb, s_ri);
  }
  float o2r = softshrink(s_rr - s_ii + b2[t]);
  float o2i = softshrink(s_ir + s_ri + b2[256 + t]);
  amp[t] = sqrtf(o2r * o2r + o2i * o2i + 1e-12f);
  __syncthreads();
  if (t < NEXP) {
    float s = 0.f;
    for (int k = 0; k < 256; ++k) s = fmaf(amp[k], w_gate[k * NEXP + t], s);
    ws[WS_LG + b * NEXP + t] = s;
  }
}

// ---------------------------------------------------------------------------
// G4: top-5 + softmax -> gates, written into d_out tail (output 1)
// ---------------------------------------------------------------------------
__global__ void k_gates(const float* __restrict__ ws, float* __restrict__ out) {
  __shared__ float lg[8][NEXP];
  int t = threadIdx.x;
  for (int z = t; z < 8 * NEXP; z += 64) (&lg[0][0])[z] = ws[WS_LG + z];
  __syncthreads();
  if (t < 8) {
    float vals[5]; int idx[5];
    for (int r = 0; r < 5; ++r) {
      float best = -INFINITY; int bi = 0;
      for (int e = 0; e < NEXP; ++e) {
        float v = lg[t][e];
        if (v > best) { best = v; bi = e; }     // strict > keeps lowest index on ties
      }
      vals[r] = best; idx[r] = bi; lg[t][bi] = -INFINITY;
    }
    float den = 0.f, wv[5];
    for (int r = 0; r < 5; ++r) { wv[r] = expf(vals[r] - vals[0]); den += wv[r]; }
    float g[NEXP];
    for (int e = 0; e < NEXP; ++e) g[e] = 0.f;
    for (int r = 0; r < 5; ++r) g[idx[r]] = wv[r] / den;
    for (int e = 0; e < NEXP; ++e) out[GATES_OFF + (size_t)t * NEXP + e] = g[e];
  }
}

// ---------------------------------------------------------------------------
// PE: 2D sinusoid tables (double precision, cast f32)
// ---------------------------------------------------------------------------
__global__ void k_pe(float* __restrict__ ws) {
  int idx = blockIdx.x * 256 + threadIdx.x;     // 272*256 = 69632 = 4096 + 65536
  const double K = 0.03597789207803196;         // ln(10000)/256
  if (idx < 4096) {
    int c = idx >> 8, dd = idx & 255;
    double ang = (double)c * exp(-(double)(dd & ~1) * K);
    ws[WS_PEF + idx] = (float)((dd & 1) ? cos(ang) : sin(ang));
  } else {
    int r = idx - 4096;
    int mm = r >> 8, jj = r & 255;
    double ang = (double)mm * exp(-(double)(jj & ~1) * K);
    ws[WS_PEP + r] = (float)((jj & 1) ? cos(ang) : sin(ang));
  }
}

// ---------------------------------------------------------------------------
// E: patch embedding. One block per (tile, b); tile = (expert, patch m, c-group).
// CPG = channels per block = 16/split. Inactive experts: stream zeros.
// ---------------------------------------------------------------------------
template <int CPG>
__global__ __launch_bounds__(256)
void k_embed(const float* __restrict__ x, const float* __restrict__ Wv,
             const float* __restrict__ ws, float* __restrict__ out, int tile_base) {
  constexpr int SPLIT = 16 / CPG;
  __shared__ __align__(16) float xl[896];       // max p*CPG = 56*16
  int tile = tile_base + blockIdx.x;
  int b = blockIdx.y, t = threadIdx.x;

  int i = 0;
  while (tile >= TBL.T0[i + 1]) ++i;            // uniform scalar search (<=43 iters)
  int p = TBL.P[i];
  int local = tile - TBL.T0[i];
  int m, cg;
  if (SPLIT == 1) { m = local; cg = 0; }
  else            { m = local / SPLIT; cg = local % SPLIT; }
  int c0 = cg * CPG;
  int g  = TBL.G0[i] + m;
  int d0 = 2 * t;

  float gate = out[GATES_OFF + (size_t)b * NEXP + i];
  size_t obase = (((size_t)(b * 16 + c0) * NTOT) + g) * 512 + d0;
  const size_t cstride = (size_t)NTOT * 512;

  if (gate > 0.f) {
    int tot = p * CPG;
    for (int id = t; id < tot; id += 256) {
      int q = id / CPG, cc = id % CPG;
      int l = m * p + q; l = l > 511 ? 511 : l;  // ReplicationPad1d (edge)
      xl[id] = x[((size_t)b * 512 + l) * 16 + c0 + cc];
    }
    __syncthreads();

    v2f acc[CPG];
#pragma unroll
    for (int cc = 0; cc < CPG; ++cc) { acc[cc].x = 0.f; acc[cc].y = 0.f; }
    const float* wp = Wv + (size_t)i * 262144 + d0;   // Wv[i][q][d0..d0+1]
    for (int q = 0; q < p; ++q) {
      v2f w = *(const v2f*)(wp + (size_t)q * 512);
      const float* xq = xl + q * CPG;
#pragma unroll
      for (int cc = 0; cc < CPG; ++cc) {
        float xv = xq[cc];
        acc[cc].x = fmaf(xv, w.x, acc[cc].x);
        acc[cc].y = fmaf(xv, w.y, acc[cc].y);
      }
    }

    v2f pe[CPG];
    if (d0 < 256) {                               // feature half (wave-uniform)
#pragma unroll
      for (int cc = 0; cc < CPG; ++cc)
        pe[cc] = *(const v2f*)(ws + WS_PEF + (c0 + cc) * 256 + d0);
    } else {                                      // position half
      v2f pp = *(const v2f*)(ws + WS_PEP + m * 256 + (d0 - 256));
#pragma unroll
      for (int cc = 0; cc < CPG; ++cc) pe[cc] = pp;
    }
#pragma unroll
    for (int cc = 0; cc < CPG; ++cc) {
      v2f v; v.x = acc[cc].x + pe[cc].x; v.y = acc[cc].y + pe[cc].y;
      __builtin_nontemporal_store(v, (v2f*)(out + obase + (size_t)cc * cstride));
    }
  } else {
    v2f z; z.x = 0.f; z.y = 0.f;
#pragma unroll
    for (int cc = 0; cc < CPG; ++cc)
      __builtin_nontemporal_store(z, (v2f*)(out + obase + (size_t)cc * cstride));
  }
}

// ---------------------------------------------------------------------------
extern "C" void kernel_launch(void* const* d_in, const int* in_sizes, int n_in,
                              void* d_out, int out_size, void* d_ws, size_t ws_size,
                              hipStream_t stream) {
  const float* x       = (const float*)d_in[0];
  const float* w_start = (const float*)d_in[1];
  const float* b_start = (const float*)d_in[2];
  const float* w1      = (const float*)d_in[3];
  const float* b1      = (const float*)d_in[4];
  const float* w2      = (const float*)d_in[5];
  const float* b2      = (const float*)d_in[6];
  const float* w_gate  = (const float*)d_in[7];
  const float* Wv      = (const float*)d_in[8];
  float* out = (float*)d_out;
  float* ws  = (float*)d_ws;

  k_dft  <<<8,   256, 0, stream>>>(x, w_start, b_start, ws);
  k_fc1  <<<32,  256, 0, stream>>>(w1, b1, ws);
  k_fc2  <<<8,   256, 0, stream>>>(w2, b2, w_gate, ws);
  k_gates<<<1,    64, 0, stream>>>(ws, out);
  k_pe   <<<272, 256, 0, stream>>>(ws);

  int i = 0;
  while (i < NEXP) {
    int sl = HTBL.SL[i];
    int j = i;
    while (j < NEXP && HTBL.SL[j] == sl) ++j;
    int base = HTBL.T0[i];
    int cnt  = HTBL.T0[j] - base;
    dim3 grid(cnt, 8);
    switch (sl) {
      case 0: k_embed<16><<<grid, 256, 0, stream>>>(x, Wv, ws, out, base); break;
      case 1: k_embed<8> <<<grid, 256, 0, stream>>>(x, Wv, ws, out, base); break;
      case 2: k_embed<4> <<<grid, 256, 0, stream>>>(x, Wv, ws, out, base); break;
      case 3: k_embed<2> <<<grid, 256, 0, stream>>>(x, Wv, ws, out, base); break;
      case 4: k_embed<1> <<<grid, 256, 0, stream>>>(x, Wv, ws, out, base); break;
    }
    i = j;
  }
}

// Round 2
// 605.519 us; speedup vs baseline: 1.0664x; 1.0664x over previous
//
#include <hip/hip_runtime.h>
#include <math.h>

// ---------------------------------------------------------------------------
// L=512, C=16, B=8, D=512, TOP_K=5, E=43 experts
// out0: emb_all [8, 16, 1657, 512] f32 ; out1: gates [8, 43] f32
// Strategy: (1) linear dwordx4 zero-fill of out0 at HBM rate (proven 6.35 TB/s
// pattern); (2) embed kernel stores ONLY active (b,expert) rows (~12%);
// (3) gating chain widened + fused (4 launches).
// ---------------------------------------------------------------------------

typedef float v4f __attribute__((ext_vector_type(4)));

constexpr int NEXP = 43;
constexpr int NTOT = 1657;
constexpr long long GATES_OFF = 108593152LL;   // 8*16*1657*512
constexpr int OUT_V4 = 27148288;               // out0 floats / 4

// workspace float offsets
constexpr int WS_XR  = 0;       // [8,256]
constexpr int WS_XI  = 2048;    // [8,256]
constexpr int WS_O1R = 4096;    // [8,1024]
constexpr int WS_O1I = 12288;   // [8,1024]
constexpr int WS_P2  = 20480;   // [8,4,4,256] fc2 partials
constexpr int WS_PEF = 53248;   // pe_feat [16,256]
constexpr int WS_PEP = 57344;   // pe_pos  [256,256]

struct Tables {
  int P[NEXP], N[NEXP], SP[NEXP], G0[NEXP], T0[NEXP+1], TB[5], ne;
};
constexpr int split_of(int p) { return p >= 170 ? 8 : p >= 102 ? 4 : p >= 64 ? 2 : 1; }

constexpr Tables make_tables() {
  Tables t{};
  int ne = 0;
  for (int p = 2; p <= 512; ++p) {
    int k = 512 / p;
    if (k >= 1 && 512 / k == p) t.P[ne++] = p;
  }
  t.ne = ne;
  int g = 0, tl = 0;
  for (int i = 0; i < ne; ++i) {
    int p = t.P[i], n = (512 + p - 1) / p;
    t.N[i] = n; t.SP[i] = split_of(p);
    t.G0[i] = g;  g += n;
    t.T0[i] = tl; tl += n * t.SP[i];
  }
  t.T0[ne] = tl;
  t.TB[0] = 0;
  for (int l = 0; l < 4; ++l) {
    int s = (l == 0) ? 1 : (l == 1) ? 2 : (l == 2) ? 4 : 8;
    int a = 0;
    for (int i = 0; i < ne; ++i) if (t.SP[i] <= s) a += t.N[i] * t.SP[i];
    t.TB[l + 1] = a;
  }
  return t;
}
constexpr Tables HTBL = make_tables();
static_assert(HTBL.ne == 43, "expert count");
static_assert(HTBL.G0[42] + HTBL.N[42] == NTOT, "total patches");
static_assert(HTBL.T0[43] == 1759, "total tiles");
static_assert(HTBL.TB[4] == 1759, "boundaries");

constexpr int NTILE = 1759;
struct TileMap { int v[NTILE]; };
constexpr TileMap make_tmap() {
  TileMap tm{};
  int idx = 0;
  for (int i = 0; i < HTBL.ne; ++i)
    for (int m = 0; m < HTBL.N[i]; ++m)
      for (int cg = 0; cg < HTBL.SP[i]; ++cg)
        tm.v[idx++] = i | (m << 6) | (cg << 15);
  return tm;
}
__constant__ TileMap TMAPC = make_tmap();
__constant__ Tables  TBLC  = make_tables();

// ---------------------------------------------------------------------------
// k_pre: blocks 0..7 -> DFT path (xs = x@w_start+b, rFFT ortho, drop DC)
//        blocks 8..279 -> positional-embedding tables (f32)
// ---------------------------------------------------------------------------
__global__ void k_pre(const float* __restrict__ x, const float* __restrict__ w_start,
                      const float* __restrict__ b_start, float* __restrict__ ws) {
  if (blockIdx.x < 8) {
    __shared__ float xs[512];
    int b = blockIdx.x, t = threadIdx.x;
    float w[16];
#pragma unroll
    for (int c = 0; c < 16; ++c) w[c] = w_start[c];
    float bs = b_start[0];
    for (int l = t; l < 512; l += 256) {
      const float* xp = x + ((size_t)b * 512 + l) * 16;
      float s = bs;
#pragma unroll
      for (int c = 0; c < 16; ++c) s = fmaf(xp[c], w[c], s);
      xs[l] = s;
    }
    __syncthreads();
    int k = t + 1;                       // freqs 1..256
    float ar = 0.f, ai = 0.f;
    int ph = 0;                          // exact integer phase mod 512
    for (int l = 0; l < 512; ++l) {
      float a = (float)ph * (1.0f / 256.0f);
      float v = xs[l];
      ar = fmaf(v,  cospif(a), ar);
      ai = fmaf(-v, sinpif(a), ai);
      ph = (ph + k) & 511;
    }
    const float sc = 0.044194173824159216f;   // 1/sqrt(512)
    ws[WS_XR + b * 256 + t] = ar * sc;
    ws[WS_XI + b * 256 + t] = ai * sc;
  } else {
    int idx = (blockIdx.x - 8) * 256 + threadIdx.x;   // 272*256 = 4096 + 65536
    const float K = 0.03597789207803197f;             // ln(10000)/256
    if (idx < 4096) {
      int c = idx >> 8, d = idx & 255;
      float ang = (float)c * expf(-(float)(d & ~1) * K);
      ws[WS_PEF + idx] = (d & 1) ? cosf(ang) : sinf(ang);
    } else {
      int r = idx - 4096, mm = r >> 8, j = r & 255;
      float ang = (float)mm * expf(-(float)(j & ~1) * K);
      ws[WS_PEP + r] = (j & 1) ? cosf(ang) : sinf(ang);
    }
  }
}

// ---------------------------------------------------------------------------
// k_fc1: complex 256 -> 1024 + relu   (32 blocks: b x 4 j-chunks)
// ---------------------------------------------------------------------------
__global__ void k_fc1(const float* __restrict__ w1, const float* __restrict__ b1,
                      float* __restrict__ ws) {
  __shared__ float xr[256], xi[256];
  int b = blockIdx.x >> 2, jg = blockIdx.x & 3, t = threadIdx.x;
  xr[t] = ws[WS_XR + b * 256 + t];
  xi[t] = ws[WS_XI + b * 256 + t];
  __syncthreads();
  int j = jg * 256 + t;
  float s_ra = 0.f, s_rb = 0.f, s_ia = 0.f, s_ib = 0.f;
  for (int k = 0; k < 256; ++k) {
    float a  = w1[k * 1024 + j];
    float bb = w1[262144 + k * 1024 + j];
    float r = xr[k], im = xi[k];
    s_ra = fmaf(r, a, s_ra);  s_ib = fmaf(im, bb, s_ib);
    s_ia = fmaf(im, a, s_ia); s_rb = fmaf(r, bb, s_rb);
  }
  ws[WS_O1R + b * 1024 + j] = fmaxf(s_ra - s_ib + b1[j], 0.f);
  ws[WS_O1I + b * 1024 + j] = fmaxf(s_ia + s_rb + b1[1024 + j], 0.f);
}

// ---------------------------------------------------------------------------
// k_fc2a: complex 1024 -> 256, k-split into 4 chunks (32 blocks: b x kc)
// ---------------------------------------------------------------------------
__global__ void k_fc2a(const float* __restrict__ w2, float* __restrict__ ws) {
  __shared__ float lr[256], li[256];
  int b = blockIdx.x >> 2, kc = blockIdx.x & 3, t = threadIdx.x;
  lr[t] = ws[WS_O1R + b * 1024 + kc * 256 + t];
  li[t] = ws[WS_O1I + b * 1024 + kc * 256 + t];
  __syncthreads();
  float s_rr = 0.f, s_ri = 0.f, s_ir = 0.f, s_ii = 0.f;
  int kb = kc * 256;
  for (int k = 0; k < 256; ++k) {
    float a  = w2[(kb + k) * 256 + t];
    float bb = w2[262144 + (kb + k) * 256 + t];
    float r = lr[k], im = li[k];
    s_rr = fmaf(r, a, s_rr);  s_ii = fmaf(im, bb, s_ii);
    s_ir = fmaf(im, a, s_ir); s_ri = fmaf(r, bb, s_ri);
  }
  float* P = ws + WS_P2 + (size_t)(b * 4 + kc) * 1024 + t;
  P[0] = s_rr; P[256] = s_ii; P[512] = s_ir; P[768] = s_ri;
}

// ---------------------------------------------------------------------------
// k_fc2b: reduce partials + softshrink + amp + logits + top5 + gates -> out
// ---------------------------------------------------------------------------
__device__ __forceinline__ float softshrink(float v) {
  const float l = 0.01f;
  return v > l ? v - l : (v < -l ? v + l : 0.f);
}

__global__ void k_fc2b(const float* __restrict__ b2, const float* __restrict__ w_gate,
                       float* __restrict__ ws, float* __restrict__ out) {
  __shared__ float amp[256], lg[64];
  int b = blockIdx.x, t = threadIdx.x;
  float s_rr = 0.f, s_ii = 0.f, s_ir = 0.f, s_ri = 0.f;
  for (int kc = 0; kc < 4; ++kc) {
    const float* P = ws + WS_P2 + (size_t)(b * 4 + kc) * 1024 + t;
    s_rr += P[0]; s_ii += P[256]; s_ir += P[512]; s_ri += P[768];
  }
  float o2r = softshrink(s_rr - s_ii + b2[t]);
  float o2i = softshrink(s_ir + s_ri + b2[256 + t]);
  amp[t] = sqrtf(o2r * o2r + o2i * o2i + 1e-12f);
  __syncthreads();
  if (t < NEXP) {
    float s = 0.f;
    for (int k = 0; k < 256; ++k) s = fmaf(amp[k], w_gate[k * NEXP + t], s);
    lg[t] = s;
  }
  __syncthreads();
  if (t == 0) {
    float v[NEXP];
    for (int e = 0; e < NEXP; ++e) v[e] = lg[e];
    float vals[5]; int idx[5];
    for (int r = 0; r < 5; ++r) {
      float best = -INFINITY; int bi = 0;
      for (int e = 0; e < NEXP; ++e)
        if (v[e] > best) { best = v[e]; bi = e; }
      vals[r] = best; idx[r] = bi; v[bi] = -INFINITY;
    }
    float den = 0.f, wv[5];
    for (int r = 0; r < 5; ++r) { wv[r] = expf(vals[r] - vals[0]); den += wv[r]; }
    float g[NEXP];
    for (int e = 0; e < NEXP; ++e) g[e] = 0.f;
    for (int r = 0; r < 5; ++r) g[idx[r]] = wv[r] / den;
    for (int e = 0; e < NEXP; ++e) out[GATES_OFF + (size_t)b * NEXP + e] = g[e];
  }
}

// ---------------------------------------------------------------------------
// k_fill: linear dwordx4 zero of out0 (434 MB) — the 6.35 TB/s pattern
// grid 13256 x 256, 8 grid-stride passes, each pass fully contiguous
// ---------------------------------------------------------------------------
__global__ void k_fill(float* __restrict__ out) {
  size_t id = (size_t)blockIdx.x * 256 + threadIdx.x;
  v4f z = {0.f, 0.f, 0.f, 0.f};
  v4f* o = (v4f*)out;
#pragma unroll
  for (int s = 0; s < 8; ++s)
    o[id + (size_t)s * 3393536] = z;    // 13256*256 = 3,393,536 ; *8 = OUT_V4
}

// ---------------------------------------------------------------------------
// k_embed<CPG>: ACTIVE blocks only compute+store; inactive exit w/o stores.
// Thread layout: 128 d-groups (16B each) x 2 channel subgroups; each thread
// owns CPT = CPG/2 channels. Wave stores are 1KB contiguous.
// ---------------------------------------------------------------------------
template <int CPG>
__global__ __launch_bounds__(256)
void k_embed(const float* __restrict__ x, const float* __restrict__ Wv,
             const float* __restrict__ ws, float* __restrict__ out, int base) {
  constexpr int CPT = CPG / 2;
  __shared__ __align__(16) float xl[1024];       // max p*CPG = 1024
  int tile = base + blockIdx.x, b = blockIdx.y, t = threadIdx.x;
  int info = TMAPC.v[tile];
  int i = info & 63, m = (info >> 6) & 511, cg = info >> 15;

  float gate = out[GATES_OFF + (size_t)b * NEXP + i];
  if (gate <= 0.f) return;                       // zeros already in place

  int p  = TBLC.P[i];
  int c0 = cg * CPG;
  int g  = TBLC.G0[i] + m;
  int dg = t & 127, tch = t >> 7;
  int d0 = dg * 4;

  int tot = p * CPG;
  for (int id = t; id < tot; id += 256) {
    int q = id / CPG, cc = id % CPG;
    int l = m * p + q; l = l > 511 ? 511 : l;    // ReplicationPad1d (edge)
    xl[id] = x[((size_t)b * 512 + l) * 16 + c0 + cc];
  }
  __syncthreads();

  v4f acc[CPT];
#pragma unroll
  for (int j = 0; j < CPT; ++j) acc[j] = (v4f){0.f, 0.f, 0.f, 0.f};
  const float* wp = Wv + (size_t)i * 262144 + d0;
  const float* xb = xl + tch * CPT;
  for (int q = 0; q < p; ++q) {
    v4f w = *(const v4f*)(wp + (size_t)q * 512);
    const float* xq = xb + q * CPG;
#pragma unroll
    for (int j = 0; j < CPT; ++j) {
      float xv = xq[j];                          // LDS broadcast
      acc[j].x = fmaf(xv, w.x, acc[j].x);
      acc[j].y = fmaf(xv, w.y, acc[j].y);
      acc[j].z = fmaf(xv, w.z, acc[j].z);
      acc[j].w = fmaf(xv, w.w, acc[j].w);
    }
  }

  int cA = c0 + tch * CPT;
  const size_t cstride = (size_t)NTOT * 512;
  size_t obase = (((size_t)(b * 16 + cA) * NTOT) + g) * 512 + d0;
  if (d0 < 256) {                                // feature half (wave-uniform)
#pragma unroll
    for (int j = 0; j < CPT; ++j) {
      v4f pe = *(const v4f*)(ws + WS_PEF + (cA + j) * 256 + d0);
      v4f v = acc[j] + pe;
      *(v4f*)(out + obase + (size_t)j * cstride) = v;
    }
  } else {                                       // position half
    v4f pe = *(const v4f*)(ws + WS_PEP + m * 256 + (d0 - 256));
#pragma unroll
    for (int j = 0; j < CPT; ++j) {
      v4f v = acc[j] + pe;
      *(v4f*)(out + obase + (size_t)j * cstride) = v;
    }
  }
}

// ---------------------------------------------------------------------------
extern "C" void kernel_launch(void* const* d_in, const int* in_sizes, int n_in,
                              void* d_out, int out_size, void* d_ws, size_t ws_size,
                              hipStream_t stream) {
  const float* x       = (const float*)d_in[0];
  const float* w_start = (const float*)d_in[1];
  const float* b_start = (const float*)d_in[2];
  const float* w1      = (const float*)d_in[3];
  const float* b1      = (const float*)d_in[4];
  const float* w2      = (const float*)d_in[5];
  const float* b2      = (const float*)d_in[6];
  const float* w_gate  = (const float*)d_in[7];
  const float* Wv      = (const float*)d_in[8];
  float* out = (float*)d_out;
  float* ws  = (float*)d_ws;

  k_pre  <<<280, 256, 0, stream>>>(x, w_start, b_start, ws);
  k_fc1  <<<32,  256, 0, stream>>>(w1, b1, ws);
  k_fc2a <<<32,  256, 0, stream>>>(w2, ws);
  k_fc2b <<<8,   256, 0, stream>>>(b2, w_gate, ws, out);
  k_fill <<<13256, 256, 0, stream>>>(out);

  k_embed<16><<<dim3(HTBL.TB[1], 8), 256, 0, stream>>>(x, Wv, ws, out, 0);
  k_embed<8> <<<dim3(HTBL.TB[2] - HTBL.TB[1], 8), 256, 0, stream>>>(x, Wv, ws, out, HTBL.TB[1]);
  k_embed<4> <<<dim3(HTBL.TB[3] - HTBL.TB[2], 8), 256, 0, stream>>>(x, Wv, ws, out, HTBL.TB[2]);
  k_embed<2> <<<dim3(HTBL.TB[4] - HTBL.TB[3], 8), 256, 0, stream>>>(x, Wv, ws, out, HTBL.TB[3]);
}

// Round 4
// 582.100 us; speedup vs baseline: 1.1093x; 1.0402x over previous
//
#include <hip/hip_runtime.h>
#include <math.h>

// ---------------------------------------------------------------------------
// L=512, C=16, B=8, D=512, TOP_K=5, E=43 experts
// out0: emb_all [8, 16, 1657, 512] f32 ; out1: gates [8, 43] f32
// Single bulk kernel writes every out0 byte exactly once:
//   per (b,c,expert) segment, chunked into <=16-patch pieces (<=32 KB),
//   inactive -> linear dwordx4 zero fill ; active -> compute + store.
// ---------------------------------------------------------------------------

typedef float v4f __attribute__((ext_vector_type(4)));

constexpr int NEXP = 43;
constexpr int NTOT = 1657;
constexpr long long GATES_OFF = 108593152LL;   // 8*16*1657*512

// workspace float offsets
constexpr int WS_XR  = 0;       // [8,256]
constexpr int WS_XI  = 2048;    // [8,256]
constexpr int WS_O1R = 4096;    // [8,1024]
constexpr int WS_O1I = 12288;   // [8,1024]
constexpr int WS_P2  = 20480;   // [8,4,4,256] fc2 partials
constexpr int WS_PEF = 53248;   // pe_feat [16,256]
constexpr int WS_PEP = 57344;   // pe_pos  [256,256]

struct Tables { int P[NEXP], N[NEXP], G0[NEXP], ne; };

constexpr Tables make_tables() {
  Tables t{};
  int ne = 0;
  for (int p = 2; p <= 512; ++p) {
    int k = 512 / p;
    if (k >= 1 && 512 / k == p) t.P[ne++] = p;
  }
  t.ne = ne;
  int g = 0;
  for (int i = 0; i < ne; ++i) {
    int p = t.P[i], n = (512 + p - 1) / p;
    t.N[i] = n; t.G0[i] = g; g += n;
  }
  return t;
}
constexpr Tables HTBL = make_tables();
static_assert(HTBL.ne == 43, "expert count");
static_assert(HTBL.G0[42] + HTBL.N[42] == NTOT, "total patches");

// chunk table: one entry per <=16-patch piece of an expert segment
constexpr int count_chunks() {
  int c = 0;
  for (int i = 0; i < HTBL.ne; ++i) c += (HTBL.N[i] + 15) / 16;
  return c;
}
constexpr int NCHUNK = count_chunks();
static_assert(NCHUNK == 122, "chunk count");

struct Chunks { int v[NCHUNK]; };
constexpr Chunks make_chunks() {
  Chunks c{}; int idx = 0;
  for (int i = 0; i < HTBL.ne; ++i) {
    int n = HTBL.N[i];
    for (int m0 = 0; m0 < n; m0 += 16) {
      int mc = (n - m0 < 16) ? (n - m0) : 16;
      c.v[idx++] = i | (m0 << 6) | (mc << 15);
    }
  }
  return c;
}
__constant__ Tables TBLC = make_tables();
__constant__ Chunks CHKC = make_chunks();

// ---------------------------------------------------------------------------
// k_pre: blocks 0..7 -> DFT path ; blocks 8..279 -> PE tables
// ---------------------------------------------------------------------------
__global__ void k_pre(const float* __restrict__ x, const float* __restrict__ w_start,
                      const float* __restrict__ b_start, float* __restrict__ ws) {
  if (blockIdx.x < 8) {
    __shared__ float xs[512];
    int b = blockIdx.x, t = threadIdx.x;
    float w[16];
#pragma unroll
    for (int c = 0; c < 16; ++c) w[c] = w_start[c];
    float bs = b_start[0];
    for (int l = t; l < 512; l += 256) {
      const float* xp = x + ((size_t)b * 512 + l) * 16;
      float s = bs;
#pragma unroll
      for (int c = 0; c < 16; ++c) s = fmaf(xp[c], w[c], s);
      xs[l] = s;
    }
    __syncthreads();
    int k = t + 1;                       // freqs 1..256
    float ar = 0.f, ai = 0.f;
    int ph = 0;                          // exact integer phase mod 512
    for (int l = 0; l < 512; ++l) {
      float a = (float)ph * (1.0f / 256.0f);
      float v = xs[l];
      ar = fmaf(v,  cospif(a), ar);
      ai = fmaf(-v, sinpif(a), ai);
      ph = (ph + k) & 511;
    }
    const float sc = 0.044194173824159216f;   // 1/sqrt(512)
    ws[WS_XR + b * 256 + t] = ar * sc;
    ws[WS_XI + b * 256 + t] = ai * sc;
  } else {
    int idx = (blockIdx.x - 8) * 256 + threadIdx.x;   // 272*256 = 4096 + 65536
    const float K = 0.03597789207803197f;             // ln(10000)/256
    if (idx < 4096) {
      int c = idx >> 8, d = idx & 255;
      float ang = (float)c * expf(-(float)(d & ~1) * K);
      ws[WS_PEF + idx] = (d & 1) ? cosf(ang) : sinf(ang);
    } else {
      int r = idx - 4096, mm = r >> 8, j = r & 255;
      float ang = (float)mm * expf(-(float)(j & ~1) * K);
      ws[WS_PEP + r] = (j & 1) ? cosf(ang) : sinf(ang);
    }
  }
}

// ---------------------------------------------------------------------------
// k_fc1: complex 256 -> 1024 + relu   (32 blocks: b x 4 j-chunks)
// ---------------------------------------------------------------------------
__global__ void k_fc1(const float* __restrict__ w1, const float* __restrict__ b1,
                      float* __restrict__ ws) {
  __shared__ float xr[256], xi[256];
  int b = blockIdx.x >> 2, jg = blockIdx.x & 3, t = threadIdx.x;
  xr[t] = ws[WS_XR + b * 256 + t];
  xi[t] = ws[WS_XI + b * 256 + t];
  __syncthreads();
  int j = jg * 256 + t;
  float s_ra = 0.f, s_rb = 0.f, s_ia = 0.f, s_ib = 0.f;
  for (int k = 0; k < 256; ++k) {
    float a  = w1[k * 1024 + j];
    float bb = w1[262144 + k * 1024 + j];
    float r = xr[k], im = xi[k];
    s_ra = fmaf(r, a, s_ra);  s_ib = fmaf(im, bb, s_ib);
    s_ia = fmaf(im, a, s_ia); s_rb = fmaf(r, bb, s_rb);
  }
  ws[WS_O1R + b * 1024 + j] = fmaxf(s_ra - s_ib + b1[j], 0.f);
  ws[WS_O1I + b * 1024 + j] = fmaxf(s_ia + s_rb + b1[1024 + j], 0.f);
}

// ---------------------------------------------------------------------------
// k_fc2a: complex 1024 -> 256, k-split x4 (32 blocks)
// ---------------------------------------------------------------------------
__global__ void k_fc2a(const float* __restrict__ w2, float* __restrict__ ws) {
  __shared__ float lr[256], li[256];
  int b = blockIdx.x >> 2, kc = blockIdx.x & 3, t = threadIdx.x;
  lr[t] = ws[WS_O1R + b * 1024 + kc * 256 + t];
  li[t] = ws[WS_O1I + b * 1024 + kc * 256 + t];
  __syncthreads();
  float s_rr = 0.f, s_ri = 0.f, s_ir = 0.f, s_ii = 0.f;
  int kb = kc * 256;
  for (int k = 0; k < 256; ++k) {
    float a  = w2[(kb + k) * 256 + t];
    float bb = w2[262144 + (kb + k) * 256 + t];
    float r = lr[k], im = li[k];
    s_rr = fmaf(r, a, s_rr);  s_ii = fmaf(im, bb, s_ii);
    s_ir = fmaf(im, a, s_ir); s_ri = fmaf(r, bb, s_ri);
  }
  float* P = ws + WS_P2 + (size_t)(b * 4 + kc) * 1024 + t;
  P[0] = s_rr; P[256] = s_ii; P[512] = s_ir; P[768] = s_ri;
}

// ---------------------------------------------------------------------------
// k_fc2b: reduce + softshrink + amp + logits + top5 + softmax -> gates
// ---------------------------------------------------------------------------
__device__ __forceinline__ float softshrink(float v) {
  const float l = 0.01f;
  return v > l ? v - l : (v < -l ? v + l : 0.f);
}

__global__ void k_fc2b(const float* __restrict__ b2, const float* __restrict__ w_gate,
                       float* __restrict__ ws, float* __restrict__ out) {
  __shared__ float amp[256], lg[64];
  int b = blockIdx.x, t = threadIdx.x;
  float s_rr = 0.f, s_ii = 0.f, s_ir = 0.f, s_ri = 0.f;
  for (int kc = 0; kc < 4; ++kc) {
    const float* P = ws + WS_P2 + (size_t)(b * 4 + kc) * 1024 + t;
    s_rr += P[0]; s_ii += P[256]; s_ir += P[512]; s_ri += P[768];
  }
  float o2r = softshrink(s_rr - s_ii + b2[t]);
  float o2i = softshrink(s_ir + s_ri + b2[256 + t]);
  amp[t] = sqrtf(o2r * o2r + o2i * o2i + 1e-12f);
  __syncthreads();
  if (t < NEXP) {
    float s = 0.f;
    for (int k = 0; k < 256; ++k) s = fmaf(amp[k], w_gate[k * NEXP + t], s);
    lg[t] = s;
  }
  __syncthreads();
  if (t == 0) {
    float v[NEXP];
    for (int e = 0; e < NEXP; ++e) v[e] = lg[e];
    float vals[5]; int idx[5];
    for (int r = 0; r < 5; ++r) {
      float best = -INFINITY; int bi = 0;
      for (int e = 0; e < NEXP; ++e)
        if (v[e] > best) { best = v[e]; bi = e; }
      vals[r] = best; idx[r] = bi; v[bi] = -INFINITY;
    }
    float den = 0.f, wv[5];
    for (int r = 0; r < 5; ++r) { wv[r] = expf(vals[r] - vals[0]); den += wv[r]; }
    float g[NEXP];
    for (int e = 0; e < NEXP; ++e) g[e] = 0.f;
    for (int r = 0; r < 5; ++r) g[idx[r]] = wv[r] / den;
    for (int e = 0; e < NEXP; ++e) out[GATES_OFF + (size_t)b * NEXP + e] = g[e];
  }
}

// ---------------------------------------------------------------------------
// k_main: grid (122 chunks, 128 bc). Each block owns one contiguous run of
// out0 (<=16 patches * 2KB). Inactive -> linear v4 zero fill. Active ->
// per-thread v4 dot over p + PE, linear v4 store.
// ---------------------------------------------------------------------------
__global__ __launch_bounds__(256)
void k_main(const float* __restrict__ x, const float* __restrict__ Wv,
            const float* __restrict__ ws, float* __restrict__ out) {
  int desc = CHKC.v[blockIdx.x];
  int i = desc & 63, m0 = (desc >> 6) & 511, mc = desc >> 15;
  int bc = blockIdx.y, b = bc >> 4, c = bc & 15;
  int t = threadIdx.x;

  float gate = out[GATES_OFF + (size_t)b * NEXP + i];
  int g0 = TBLC.G0[i] + m0;
  size_t base = ((size_t)bc * NTOT + g0) * 512;

  if (gate <= 0.f) {                       // linear zero fill, 1KB/wave-instr
    v4f z = {0.f, 0.f, 0.f, 0.f};
    v4f* o = (v4f*)(out + base);
    int nv = mc * 128;
    for (int v = t; v < nv; v += 256) o[v] = z;
    return;
  }

  int p = TBLC.P[i];
  __shared__ float xl[512];
  for (int l = t; l < 512; l += 256)
    xl[l] = x[((size_t)b * 512 + l) * 16 + c];   // x[b, :, c]
  __syncthreads();

  int dg = t & 127, d0 = dg * 4, ps = t >> 7;    // 128 d-groups x 2 patches
  const float* wp = Wv + (size_t)i * 262144 + d0;
  for (int mm = ps; mm < mc; mm += 2) {
    int m = m0 + mm;
    int lb = m * p;
    v4f acc = {0.f, 0.f, 0.f, 0.f};
    for (int q = 0; q < p; ++q) {
      int l = lb + q; l = l > 511 ? 511 : l;     // ReplicationPad1d (edge)
      float xv = xl[l];                          // LDS broadcast
      v4f w = *(const v4f*)(wp + (size_t)q * 512);
      acc.x = fmaf(xv, w.x, acc.x);
      acc.y = fmaf(xv, w.y, acc.y);
      acc.z = fmaf(xv, w.z, acc.z);
      acc.w = fmaf(xv, w.w, acc.w);
    }
    v4f pe = (d0 < 256)                           // wave-uniform branch
      ? *(const v4f*)(ws + WS_PEF + c * 256 + d0)
      : *(const v4f*)(ws + WS_PEP + m * 256 + (d0 - 256));
    v4f r = acc + pe;
    *(v4f*)(out + base + (size_t)mm * 512 + d0) = r;
  }
}

// ---------------------------------------------------------------------------
extern "C" void kernel_launch(void* const* d_in, const int* in_sizes, int n_in,
                              void* d_out, int out_size, void* d_ws, size_t ws_size,
                              hipStream_t stream) {
  const float* x       = (const float*)d_in[0];
  const float* w_start = (const float*)d_in[1];
  const float* b_start = (const float*)d_in[2];
  const float* w1      = (const float*)d_in[3];
  const float* b1      = (const float*)d_in[4];
  const float* w2      = (const float*)d_in[5];
  const float* b2      = (const float*)d_in[6];
  const float* w_gate  = (const float*)d_in[7];
  const float* Wv      = (const float*)d_in[8];
  float* out = (float*)d_out;
  float* ws  = (float*)d_ws;

  k_pre  <<<280, 256, 0, stream>>>(x, w_start, b_start, ws);
  k_fc1  <<<32,  256, 0, stream>>>(w1, b1, ws);
  k_fc2a <<<32,  256, 0, stream>>>(w2, ws);
  k_fc2b <<<8,   256, 0, stream>>>(b2, w_gate, ws, out);
  k_main <<<dim3(NCHUNK, 128), 256, 0, stream>>>(x, Wv, ws, out);
}